// Round 5
// baseline (216.515 us; speedup 1.0000x reference)
//
#include <hip/hip_runtime.h>
#include <hip/hip_bf16.h>

// VectorQuantizer on MI355X — single-pass bf16 MFMA screening GEMM with
// packed-key top-2 trackers + exact fp64 resolution of banded rows.
// Phase 1 (vq_main): d' = 1 + |e|^2 - 2*(zh . eh) per (row,code) via
//   mfma_f32_16x16x32_bf16; per-lane tracker keeps top-2 keys
//   key = bits(d') & ~31 | chunk  (d' > 0 always, bits are order-preserving;
//   code = chunk*32 + entry). Rows with any other code within BAND1=1e-3 of
//   the min are recorded (winner + <=3 cands + optional tracker-scan id).
//   Bernstein bound: per-code screening error eps_d has sigma 3.9e-5,
//   fat-term 8.8e-5 -> P(miss at margin ~9.5e-4) ~ e^-29. Round-4 pass
//   empirically anchors the reference rounding zone Z_ref <= 4e-5.
// Phase 2 (vq_fix2): per flagged row, exact numpy-fp32-pipeline emulation
//   (fp64 tree dot -> f32; A = fl(zn + e2); d = fl(A - 2t); lowest-index
//   ties) over the candidate set; overwrites idx and z_q row.
// d_out: z_q 8388608 f32, then indices 32768 as f32.

#define DEVI __device__ __forceinline__

typedef __attribute__((ext_vector_type(8))) short bf16x8;
typedef __attribute__((ext_vector_type(4))) float f32x4;

#define C_DIM   256
#define K_CODES 1024
#define S_DIM   8192
#define N_ROWS  32768
#define ZQ_ELEMS 8388608
#define TILE_M  64
#define NCHUNK  32
#define BAND1   1.0e-3f
#define REC_CAP 12288
#define FLT_BIG 3.402823466e+38f

DEVI unsigned short f2b(float f) {                 // fp32 -> bf16 RNE
    unsigned u = __float_as_uint(f);
    u += 0x7FFFu + ((u >> 16) & 1u);
    return (unsigned short)(u >> 16);
}
DEVI unsigned umin2(unsigned a, unsigned b) { return a < b ? a : b; }
DEVI unsigned umax2(unsigned a, unsigned b) { return a > b ? a : b; }

DEVI f32x4 MF(bf16x8 a, bf16x8 b, f32x4 c) {
    return __builtin_amdgcn_mfma_f32_16x16x32_bf16(a, b, c, 0, 0, 0);
}
DEVI bf16x8 ldsfrag(const char* L, int row, int coff) {
    const int byte = row * 512 + (coff ^ ((row & 7) << 4));
    return *reinterpret_cast<const bf16x8*>(L + byte);
}
DEVI void gll16(const void* g, void* l) {          // 16B global -> LDS DMA
    __builtin_amdgcn_global_load_lds(
        (const __attribute__((address_space(1))) unsigned int*)g,
        (__attribute__((address_space(3))) unsigned int*)l, 16, 0, 0);
}

// ---- prologue: codebook -> bf16 hi (pre-swizzled rows) + exact f32 norms ----
__global__ void vq_prep(const float* __restrict__ E,
                        unsigned short* __restrict__ ehi,
                        float* __restrict__ e2f) {
    const int k = blockIdx.x;          // 1024 blocks
    const int lane = threadIdx.x;      // 64 threads, 8B granule each
    const float4 v = reinterpret_cast<const float4*>(E + (size_t)k * C_DIM)[lane];
    double s = (double)v.x * v.x + (double)v.y * v.y
             + (double)v.z * v.z + (double)v.w * v.w;
    ushort4 h;
    h.x = f2b(v.x); h.y = f2b(v.y); h.z = f2b(v.z); h.w = f2b(v.w);
    const int phys8 = ((((lane >> 1) ^ (k & 7)) << 1) | (lane & 1));
    reinterpret_cast<ushort4*>(ehi + (size_t)k * C_DIM)[phys8] = h;
#pragma unroll
    for (int m = 32; m; m >>= 1) s += __shfl_xor(s, m, 64);
    if (lane == 0) e2f[k] = (float)s;   // fp64-exact -> f32
}

// ---------------- phase 1 ----------------
__global__ __launch_bounds__(256, 2) void vq_main(
        const float* __restrict__ z, const float* __restrict__ E,
        const unsigned short* __restrict__ ehi,
        const float* __restrict__ e2f,
        float* __restrict__ out_zq, float* __restrict__ out_idx,
        int* __restrict__ gcnt, int* __restrict__ grec) {
    // smraw phases: A-hi stage 32KB -> B dbuf 2x16KB -> key dump 17.4KB
    //               -> epilogue transpose [32][257] f32 (32.9KB)
    __shared__ __align__(16) char smraw[32896];
    __shared__ float e2p[1024];        // 1.0f + |e_k|^2
    __shared__ int   kfinA[64];

    const int tid = threadIdx.x;
    const int n0 = blockIdx.x * TILE_M;
    const int b  = n0 >> 13;
    const int s0 = n0 & (S_DIM - 1);

    {   // e2p load
        const float4 v = reinterpret_cast<const float4*>(e2f)[tid];
        float4 w; w.x = 1.0f + v.x; w.y = 1.0f + v.y;
        w.z = 1.0f + v.z; w.w = 1.0f + v.w;
        reinterpret_cast<float4*>(e2p)[tid] = w;
    }

    // ---- stage A tile (hi only): z rows -> bf16, swizzled [64][512B] ----
    {
        const int s  = tid & 63;
        const int cg = tid >> 6;
        const float* zb = z + (size_t)b * (C_DIM * S_DIM) + s0 + s;
#pragma unroll
        for (int ci = 0; ci < 16; ++ci) {
            const int c = cg * 4 + ci * 16;
            ushort4 h;
            h.x = f2b(zb[(size_t)(c + 0) * S_DIM]);
            h.y = f2b(zb[(size_t)(c + 1) * S_DIM]);
            h.z = f2b(zb[(size_t)(c + 2) * S_DIM]);
            h.w = f2b(zb[(size_t)(c + 3) * S_DIM]);
            const int byte = s * 512 + ((c * 2) ^ ((s & 7) << 4));
            *reinterpret_cast<ushort4*>(smraw + byte) = h;
        }
    }
    __syncthreads();

    const int w    = tid >> 6;
    const int lane = tid & 63;
    const int wm   = w >> 1, wn = w & 1;   // wave: rows wm*32+.., cols wn*16+..
    const int q    = lane >> 4, jj = lane & 15;
    const int mycol = wn * 16 + jj;        // tracker/entry id 0..31

    bf16x8 Ah0[8], Ah1[8];
    {
        const int r0 = wm * 32 + jj, r1 = r0 + 16;
#pragma unroll
        for (int ks = 0; ks < 8; ++ks) {
            const int coff = ks * 64 + q * 16;
            Ah0[ks] = ldsfrag(smraw, r0, coff);
            Ah1[ks] = ldsfrag(smraw, r1, coff);
        }
    }
    __syncthreads();                       // A region -> B dbuf

    // B staging: chunk = 16KB = 16 x 1KB units; wave w stages units w*4..w*4+3
#define STAGE(N, BUF)                                                         \
    { _Pragma("unroll")                                                       \
      for (int i_ = 0; i_ < 4; ++i_) {                                        \
          const int j_ = w * 4 + i_;                                          \
          gll16((const char*)ehi + ((size_t)(N) * 16 + j_) * 1024             \
                    + (size_t)lane * 16,                                      \
                smraw + (BUF) * 16384 + j_ * 1024);                           \
      } }

    STAGE(0, 0)
    __syncthreads();                       // gll(0) landed
    STAGE(1, 1)

    const int browbyte = mycol * 512;
    const int t0x = (q * 16) ^ ((jj & 7) << 4);

    unsigned K1[8], K2[8];
#pragma unroll
    for (int i = 0; i < 8; ++i) { K1[i] = 0xFFFFFFFFu; K2[i] = 0xFFFFFFFFu; }

#define COMPUTE(N, A0, A1)                                                    \
    { const char* Lb = smraw + ((N) & 1) * 16384 + browbyte;                  \
      A0 = (f32x4){0.f, 0.f, 0.f, 0.f}; A1 = A0;                              \
      _Pragma("unroll")                                                       \
      for (int ks = 0; ks < 8; ++ks) {                                        \
          const bf16x8 bh = *reinterpret_cast<const bf16x8*>(                 \
              Lb + ((ks * 64) ^ t0x));                                        \
          A0 = MF(Ah0[ks], bh, A0); A1 = MF(Ah1[ks], bh, A1);                 \
      } }

#define UPD(A0, A1, E2V, N)                                                   \
    { _Pragma("unroll")                                                       \
      for (int r = 0; r < 4; ++r) {                                           \
          unsigned t_ = (__float_as_uint(                                     \
              __builtin_fmaf(-2.f, A0[r], E2V)) & 0xFFFFFFE0u) | (unsigned)(N);\
          unsigned lo_ = umin2(K1[r], t_), hi_ = umax2(K1[r], t_);            \
          K1[r] = lo_; K2[r] = umin2(K2[r], hi_);                             \
          t_ = (__float_as_uint(                                              \
              __builtin_fmaf(-2.f, A1[r], E2V)) & 0xFFFFFFE0u) | (unsigned)(N);\
          lo_ = umin2(K1[4 + r], t_); hi_ = umax2(K1[4 + r], t_);             \
          K1[4 + r] = lo_; K2[4 + r] = umin2(K2[4 + r], hi_);                 \
      } }

    f32x4 aA0, aA1, aB0, aB1;
    float e2A, e2B;
    COMPUTE(0, aA0, aA1); e2A = e2p[mycol];

    for (int p = 0; p < 15; ++p) {
        const int n1 = 2 * p + 1;
        __syncthreads();                   // buf(n1) ready; buf(n1+1 dest) free
        STAGE(n1 + 1, 0)
        COMPUTE(n1, aB0, aB1); e2B = e2p[n1 * 32 + mycol];
        UPD(aA0, aA1, e2A, n1 - 1)         // deferred: overlaps MFMA above
        const int n2 = 2 * p + 2;
        __syncthreads();
        if (n2 + 1 < NCHUNK) STAGE(n2 + 1, 1)
        COMPUTE(n2, aA0, aA1); e2A = e2p[n2 * 32 + mycol];
        UPD(aB0, aB1, e2B, n2 - 1)
    }
    __syncthreads();
    COMPUTE(31, aB0, aB1); e2B = e2p[31 * 32 + mycol];
    UPD(aA0, aA1, e2A, 30)
    UPD(aB0, aB1, e2B, 31)

    // ---- dump per-tracker top-2 keys: [64 rows][32 entries] int2, 272B rows
    __syncthreads();
#pragma unroll
    for (int t = 0; t < 2; ++t) {
#pragma unroll
        for (int r = 0; r < 4; ++r) {
            const int sl = t * 4 + r;
            const int row = wm * 32 + t * 16 + q * 4 + r;
            *reinterpret_cast<int2*>(smraw + row * 272 + mycol * 8) =
                make_int2((int)K1[sl], (int)K2[sl]);
        }
    }
    __syncthreads();

    // ---- leader: winner + banded candidate records ----
    if (tid < 64) {
        const char* dmp = smraw + tid * 272;
        unsigned kmin = 0xFFFFFFFFu; int emin = 0;
#pragma unroll 4
        for (int e = 0; e < 32; ++e) {
            const unsigned k1 = (unsigned)
                reinterpret_cast<const int2*>(dmp + e * 8)->x;
            if (k1 < kmin) { kmin = k1; emin = e; }
        }
        const int kmincode = (int)((kmin & 31u) << 5) | emin;
        const float dminf = __uint_as_float(kmin & 0xFFFFFFE0u);
        const unsigned limk =
            (__float_as_uint(dminf + BAND1) & 0xFFFFFFE0u) | 31u;
        int cnt = 0, nfb = 0, fbt = 0, c0 = 0, c1 = 0, c2 = 0;
#pragma unroll 4
        for (int e = 0; e < 32; ++e) {
            const int2 v = *reinterpret_cast<const int2*>(dmp + e * 8);
            const unsigned k1 = (unsigned)v.x, k2 = (unsigned)v.y;
            if (k1 <= limk) {
                const int code = (int)((k1 & 31u) << 5) | e;
                if (code != kmincode) {
                    if (cnt == 0) c0 = code;
                    else if (cnt == 1) c1 = code;
                    else if (cnt == 2) c2 = code;
                    ++cnt;
                }
            }
            if (k2 <= limk) { ++nfb; fbt = e; }   // tracker may hide a 3rd
        }
        kfinA[tid] = kmincode;
        out_idx[n0 + tid] = (float)kmincode;      // provisional for flagged
        if (cnt > 0 || nfb > 0) {
            const int full = (cnt > 3 || nfb > 1) ? 1 : 0;
            const int slot = atomicAdd(gcnt, 1);
            if (slot < REC_CAP) {
                int* rc = grec + slot * 8;
                rc[0] = n0 + tid; rc[1] = full ? -1 : cnt; rc[2] = kmincode;
                rc[3] = c0; rc[4] = c1; rc[5] = c2; rc[6] = nfb; rc[7] = fbt;
            }
        }
    }

    // ---- epilogue: gather code rows in two 32-row halves via [32][257] f32
#pragma unroll
    for (int h = 0; h < 2; ++h) {
        __syncthreads();
        {
            const int slot = tid & 31;
            const int cg   = tid >> 5;         // 8 col groups of 32
            const int kk   = kfinA[h * 32 + slot];
            const float4* er = reinterpret_cast<const float4*>(
                E + (size_t)kk * C_DIM + cg * 32);
            float* lb = reinterpret_cast<float*>(smraw) + slot * 257 + cg * 32;
#pragma unroll
            for (int i = 0; i < 8; ++i) {
                const float4 v = er[i];
                lb[4 * i + 0] = v.x; lb[4 * i + 1] = v.y;
                lb[4 * i + 2] = v.z; lb[4 * i + 3] = v.w;
            }
        }
        __syncthreads();
        {
            const int sg = tid & 31;
            const int cg = tid >> 5;
            float* ob = out_zq + (size_t)b * (C_DIM * S_DIM) + s0 + h * 32 + sg;
            const float* lr = reinterpret_cast<const float*>(smraw) + sg * 257;
#pragma unroll
            for (int i = 0; i < 32; ++i) {
                const int c = cg * 32 + i;
                ob[(size_t)c * S_DIM] = lr[c];
            }
        }
    }
}

// ---------------- phase 2: exact resolution of flagged rows ----------------
__global__ __launch_bounds__(256) void vq_fix2(
        const float* __restrict__ z, const float* __restrict__ E,
        const float* __restrict__ e2f,
        const int* __restrict__ gcnt, const int* __restrict__ grec,
        float* __restrict__ out_zq, float* __restrict__ out_idx) {
    __shared__ float  zsh[256];
    __shared__ double dpart[4];
    __shared__ float  wbdS[4];
    __shared__ int    wbkS[4];

    const int tid = threadIdx.x;
    const int w = tid >> 6, lane = tid & 63;
    int count = gcnt[0]; if (count > REC_CAP) count = REC_CAP;

    for (int ri = blockIdx.x; ri < count; ri += gridDim.x) {
        const int* rc = grec + ri * 8;
        const int n = rc[0], ncand = rc[1], kmin = rc[2];
        const int b = n >> 13, s = n & (S_DIM - 1);
        __syncthreads();                   // guard LDS reuse across rows
        const float zc = z[((size_t)(b * C_DIM + tid)) * S_DIM + s];
        zsh[tid] = zc;
        double p = (double)zc * (double)zc;
#pragma unroll
        for (int m = 32; m; m >>= 1) p += __shfl_xor(p, m, 64);
        if (lane == 0) dpart[w] = p;
        __syncthreads();
        const float znf = (float)((dpart[0] + dpart[1]) + (dpart[2] + dpart[3]));

        float bd = FLT_BIG; int bk = 0x7fffffff;
        if (ncand >= 0) {
            const int nfb = rc[6], fbt = rc[7];
            const int total = 1 + ncand + (nfb ? 32 : 0);
            for (int ci = 0; ci < total; ++ci) {
                int k;
                if (ci == 0) k = kmin;
                else if (ci <= ncand) k = rc[2 + ci];
                else k = ((ci - 1 - ncand) << 5) | fbt;  // tracker scan
                const float ec = E[(size_t)k * C_DIM + tid];
                double dd = (double)zsh[tid] * (double)ec;
#pragma unroll
                for (int m = 32; m; m >>= 1) dd += __shfl_xor(dd, m, 64);
                __syncthreads();           // dpart free
                if (lane == 0) dpart[w] = dd;
                __syncthreads();
                const float t = (float)((dpart[0] + dpart[1])
                                      + (dpart[2] + dpart[3]));
                const float A = znf + e2f[k];
                const float d = A - 2.0f * t;
                if (d < bd || (d == bd && k < bk)) { bd = d; bk = k; }
            }
        } else {                           // rare: full 1024-code scan
            float wbd = FLT_BIG; int wbk = 0x7fffffff;
            const float4* zv = reinterpret_cast<const float4*>(zsh);
            for (int k = w; k < K_CODES; k += 4) {
                const float4 ev = reinterpret_cast<const float4*>(
                    E + (size_t)k * C_DIM)[lane];
                const float4 zl4 = zv[lane];
                double dd = (double)zl4.x * ev.x + (double)zl4.y * ev.y
                          + (double)zl4.z * ev.z + (double)zl4.w * ev.w;
#pragma unroll
                for (int m = 32; m; m >>= 1) dd += __shfl_xor(dd, m, 64);
                const float t = (float)dd;
                const float A = znf + e2f[k];
                const float d = A - 2.0f * t;
                if (d < wbd || (d == wbd && k < wbk)) { wbd = d; wbk = k; }
            }
            if (lane == 0) { wbdS[w] = wbd; wbkS[w] = wbk; }
            __syncthreads();
#pragma unroll
            for (int i = 0; i < 4; ++i) {
                const float d2 = wbdS[i]; const int k2 = wbkS[i];
                if (d2 < bd || (d2 == bd && k2 < bk)) { bd = d2; bk = k2; }
            }
        }
        if (tid == 0) out_idx[n] = (float)bk;
        out_zq[((size_t)(b * C_DIM + tid)) * S_DIM + s] =
            E[(size_t)bk * C_DIM + tid];
    }
}

extern "C" void kernel_launch(void* const* d_in, const int* in_sizes, int n_in,
                              void* d_out, int out_size, void* d_ws, size_t ws_size,
                              hipStream_t stream) {
    (void)in_sizes; (void)n_in; (void)out_size; (void)ws_size;
    const float* z = (const float*)d_in[0];
    const float* E = (const float*)d_in[1];
    char* wsb = (char*)d_ws;
    unsigned short* ehi = (unsigned short*)(wsb);            // 512KB pre-swizzled
    float* e2f = (float*)(wsb + 524288);                     // 4KB
    int*   cnt = (int*)  (wsb + 528384);
    int*   rec = (int*)  (wsb + 528448);                     // 12288 x 32B
    float* out = (float*)d_out;

    hipMemsetAsync(cnt, 0, sizeof(int), stream);
    vq_prep<<<dim3(K_CODES), dim3(64), 0, stream>>>(E, ehi, e2f);
    vq_main<<<dim3(N_ROWS / TILE_M), dim3(256), 0, stream>>>(
        z, E, ehi, e2f, out, out + ZQ_ELEMS, cnt, rec);
    vq_fix2<<<dim3(4096), dim3(256), 0, stream>>>(
        z, E, e2f, cnt, rec, out, out + ZQ_ELEMS);
}

// Round 6
// 79.797 us; speedup vs baseline: 2.7133x; 2.7133x over previous
//
#include <hip/hip_runtime.h>
#include <hip/hip_bf16.h>

// VectorQuantizer on MI355X — single-pass bf16 MFMA screening GEMM with
// packed-key top-2 trackers + wave-parallel exact fp64 resolution.
// Phase 1 (vq_main): d' = 1 + |e|^2 - 2*(zh . eh) via mfma_f32_16x16x32_bf16;
//   per-lane tracker keeps top-2 keys key = bits(d')&~31 | chunk. Rows with
//   any other code within BAND1=1e-3 of the min are recorded (winner, <=10
//   cands, <=2 suspect trackers). Also emits zT: compact f32 transpose of z
//   (coalesced), so fix2 avoids the 16x-overfetch strided gather.
// Phase 2 (vq_fix2): per record (1 block, grid-stride), exact numpy-fp32
//   pipeline (fp64 dot -> f32; A = fl(zn+e2); d = fl(A-2t); lowest-index
//   ties). Candidates parallel across the 4 waves; merged via packed u64
//   (bits(d)<<32 | k). Only changed rows rewrite idx/z_q.
// d_out: z_q 8388608 f32, then indices 32768 as f32.

#define DEVI __device__ __forceinline__

typedef __attribute__((ext_vector_type(8))) short bf16x8;
typedef __attribute__((ext_vector_type(4))) float f32x4;

#define C_DIM   256
#define K_CODES 1024
#define S_DIM   8192
#define N_ROWS  32768
#define ZQ_ELEMS 8388608
#define TILE_M  64
#define NCHUNK  32
#define BAND1   1.0e-3f
#define REC_CAP 12288
#define FLT_BIG 3.402823466e+38f

// ws layout
#define WS_EHI  0
#define WS_E2F  524288
#define WS_CNT  528384
#define WS_REC  528448            // REC_CAP x 64B
#define WS_ZT   1314880           // 32MB compact z transpose (optional)
#define WS_NEED (WS_ZT + (size_t)N_ROWS * C_DIM * 4)

DEVI unsigned short f2b(float f) {                 // fp32 -> bf16 RNE
    unsigned u = __float_as_uint(f);
    u += 0x7FFFu + ((u >> 16) & 1u);
    return (unsigned short)(u >> 16);
}
DEVI unsigned umin2(unsigned a, unsigned b) { return a < b ? a : b; }
DEVI unsigned umax2(unsigned a, unsigned b) { return a > b ? a : b; }
DEVI unsigned long long ullmin2(unsigned long long a, unsigned long long b) {
    return a < b ? a : b;
}

DEVI f32x4 MF(bf16x8 a, bf16x8 b, f32x4 c) {
    return __builtin_amdgcn_mfma_f32_16x16x32_bf16(a, b, c, 0, 0, 0);
}
DEVI bf16x8 ldsfrag(const char* L, int row, int coff) {
    const int byte = row * 512 + (coff ^ ((row & 7) << 4));
    return *reinterpret_cast<const bf16x8*>(L + byte);
}
DEVI void gll16(const void* g, void* l) {          // 16B global -> LDS DMA
    __builtin_amdgcn_global_load_lds(
        (const __attribute__((address_space(1))) unsigned int*)g,
        (__attribute__((address_space(3))) unsigned int*)l, 16, 0, 0);
}

// ---- prologue: codebook -> bf16 hi (pre-swizzled rows) + exact f32 norms ----
__global__ void vq_prep(const float* __restrict__ E,
                        unsigned short* __restrict__ ehi,
                        float* __restrict__ e2f) {
    const int k = blockIdx.x;          // 1024 blocks
    const int lane = threadIdx.x;      // 64 threads, 8B granule each
    const float4 v = reinterpret_cast<const float4*>(E + (size_t)k * C_DIM)[lane];
    double s = (double)v.x * v.x + (double)v.y * v.y
             + (double)v.z * v.z + (double)v.w * v.w;
    ushort4 h;
    h.x = f2b(v.x); h.y = f2b(v.y); h.z = f2b(v.z); h.w = f2b(v.w);
    const int phys8 = ((((lane >> 1) ^ (k & 7)) << 1) | (lane & 1));
    reinterpret_cast<ushort4*>(ehi + (size_t)k * C_DIM)[phys8] = h;
#pragma unroll
    for (int m = 32; m; m >>= 1) s += __shfl_xor(s, m, 64);
    if (lane == 0) e2f[k] = (float)s;   // fp64-exact -> f32
}

// ---------------- phase 1 ----------------
__global__ __launch_bounds__(256, 2) void vq_main(
        const float* __restrict__ z, const float* __restrict__ E,
        const unsigned short* __restrict__ ehi,
        const float* __restrict__ e2f,
        float* __restrict__ zT,            // may be null
        float* __restrict__ out_zq, float* __restrict__ out_idx,
        int* __restrict__ gcnt, int* __restrict__ grec) {
    // smraw phases: A-hi stage 32KB -> B dbuf 2x16KB -> key dump 17.4KB
    //               -> epilogue transpose [32][257] f32 (32.9KB)
    __shared__ __align__(16) char smraw[32896];
    __shared__ float e2p[1024];        // 1.0f + |e_k|^2
    __shared__ int   kfinA[64];

    const int tid = threadIdx.x;
    const int n0 = blockIdx.x * TILE_M;
    const int b  = n0 >> 13;
    const int s0 = n0 & (S_DIM - 1);

    {   // e2p load
        const float4 v = reinterpret_cast<const float4*>(e2f)[tid];
        float4 w; w.x = 1.0f + v.x; w.y = 1.0f + v.y;
        w.z = 1.0f + v.z; w.w = 1.0f + v.w;
        reinterpret_cast<float4*>(e2p)[tid] = w;
    }

    // ---- stage A tile (hi only): z rows -> bf16, swizzled [64][512B];
    //      also emit compact f32 transpose zT[n][c] (coalesced-ish 16B) ----
    {
        const int s  = tid & 63;
        const int cg = tid >> 6;
        const float* zb = z + (size_t)b * (C_DIM * S_DIM) + s0 + s;
#pragma unroll
        for (int ci = 0; ci < 16; ++ci) {
            const int c = cg * 4 + ci * 16;
            const float x0 = zb[(size_t)(c + 0) * S_DIM];
            const float x1 = zb[(size_t)(c + 1) * S_DIM];
            const float x2 = zb[(size_t)(c + 2) * S_DIM];
            const float x3 = zb[(size_t)(c + 3) * S_DIM];
            ushort4 h;
            h.x = f2b(x0); h.y = f2b(x1); h.z = f2b(x2); h.w = f2b(x3);
            const int byte = s * 512 + ((c * 2) ^ ((s & 7) << 4));
            *reinterpret_cast<ushort4*>(smraw + byte) = h;
            if (zT) {
                float4 v; v.x = x0; v.y = x1; v.z = x2; v.w = x3;
                *reinterpret_cast<float4*>(zT + (size_t)(n0 + s) * C_DIM + c) = v;
            }
        }
    }
    __syncthreads();

    const int w    = tid >> 6;
    const int lane = tid & 63;
    const int wm   = w >> 1, wn = w & 1;
    const int q    = lane >> 4, jj = lane & 15;
    const int mycol = wn * 16 + jj;        // tracker/entry id 0..31

    bf16x8 Ah0[8], Ah1[8];
    {
        const int r0 = wm * 32 + jj, r1 = r0 + 16;
#pragma unroll
        for (int ks = 0; ks < 8; ++ks) {
            const int coff = ks * 64 + q * 16;
            Ah0[ks] = ldsfrag(smraw, r0, coff);
            Ah1[ks] = ldsfrag(smraw, r1, coff);
        }
    }
    __syncthreads();                       // A region -> B dbuf

#define STAGE(N, BUF)                                                         \
    { _Pragma("unroll")                                                       \
      for (int i_ = 0; i_ < 4; ++i_) {                                        \
          const int j_ = w * 4 + i_;                                          \
          gll16((const char*)ehi + ((size_t)(N) * 16 + j_) * 1024             \
                    + (size_t)lane * 16,                                      \
                smraw + (BUF) * 16384 + j_ * 1024);                           \
      } }

    STAGE(0, 0)
    __syncthreads();                       // gll(0) landed
    STAGE(1, 1)

    const int browbyte = mycol * 512;
    const int t0x = (q * 16) ^ ((jj & 7) << 4);

    unsigned K1[8], K2[8];
#pragma unroll
    for (int i = 0; i < 8; ++i) { K1[i] = 0xFFFFFFFFu; K2[i] = 0xFFFFFFFFu; }

#define COMPUTE(N, A0, A1)                                                    \
    { const char* Lb = smraw + ((N) & 1) * 16384 + browbyte;                  \
      A0 = (f32x4){0.f, 0.f, 0.f, 0.f}; A1 = A0;                              \
      _Pragma("unroll")                                                       \
      for (int ks = 0; ks < 8; ++ks) {                                        \
          const bf16x8 bh = *reinterpret_cast<const bf16x8*>(                 \
              Lb + ((ks * 64) ^ t0x));                                        \
          A0 = MF(Ah0[ks], bh, A0); A1 = MF(Ah1[ks], bh, A1);                 \
      } }

#define UPD(A0, A1, E2V, N)                                                   \
    { _Pragma("unroll")                                                       \
      for (int r = 0; r < 4; ++r) {                                           \
          unsigned t_ = (__float_as_uint(                                     \
              __builtin_fmaf(-2.f, A0[r], E2V)) & 0xFFFFFFE0u) | (unsigned)(N);\
          unsigned lo_ = umin2(K1[r], t_), hi_ = umax2(K1[r], t_);            \
          K1[r] = lo_; K2[r] = umin2(K2[r], hi_);                             \
          t_ = (__float_as_uint(                                              \
              __builtin_fmaf(-2.f, A1[r], E2V)) & 0xFFFFFFE0u) | (unsigned)(N);\
          lo_ = umin2(K1[4 + r], t_); hi_ = umax2(K1[4 + r], t_);             \
          K1[4 + r] = lo_; K2[4 + r] = umin2(K2[4 + r], hi_);                 \
      } }

    f32x4 aA0, aA1, aB0, aB1;
    float e2A, e2B;
    COMPUTE(0, aA0, aA1); e2A = e2p[mycol];

    for (int p = 0; p < 15; ++p) {
        const int n1 = 2 * p + 1;
        __syncthreads();                   // buf(n1) ready; dest buf free
        STAGE(n1 + 1, 0)
        COMPUTE(n1, aB0, aB1); e2B = e2p[n1 * 32 + mycol];
        UPD(aA0, aA1, e2A, n1 - 1)         // deferred: overlaps MFMA above
        const int n2 = 2 * p + 2;
        __syncthreads();
        if (n2 + 1 < NCHUNK) STAGE(n2 + 1, 1)
        COMPUTE(n2, aA0, aA1); e2A = e2p[n2 * 32 + mycol];
        UPD(aB0, aB1, e2B, n2 - 1)
    }
    __syncthreads();
    COMPUTE(31, aB0, aB1); e2B = e2p[31 * 32 + mycol];
    UPD(aA0, aA1, e2A, 30)
    UPD(aB0, aB1, e2B, 31)

    // ---- dump per-tracker top-2 keys: [64 rows][32 entries] int2, 272B rows
    __syncthreads();
#pragma unroll
    for (int t = 0; t < 2; ++t) {
#pragma unroll
        for (int r = 0; r < 4; ++r) {
            const int sl = t * 4 + r;
            const int row = wm * 32 + t * 16 + q * 4 + r;
            *reinterpret_cast<int2*>(smraw + row * 272 + mycol * 8) =
                make_int2((int)K1[sl], (int)K2[sl]);
        }
    }
    __syncthreads();

    // ---- leader: winner + banded candidate records (3 passes, no scratch) --
    if (tid < 64) {
        const char* dmp = smraw + tid * 272;
        unsigned kmin = 0xFFFFFFFFu; int emin = 0;
#pragma unroll 4
        for (int e = 0; e < 32; ++e) {
            const unsigned k1 = (unsigned)
                reinterpret_cast<const int2*>(dmp + e * 8)->x;
            if (k1 < kmin) { kmin = k1; emin = e; }
        }
        const int kmincode = (int)((kmin & 31u) << 5) | emin;
        const float dminf = __uint_as_float(kmin & 0xFFFFFFE0u);
        const unsigned limk =
            (__float_as_uint(dminf + BAND1) & 0xFFFFFFE0u) | 31u;
        int cnt = 0, nfb = 0;
#pragma unroll 4
        for (int e = 0; e < 32; ++e) {
            const int2 v = *reinterpret_cast<const int2*>(dmp + e * 8);
            if ((unsigned)v.x <= limk) {
                const int code = (int)(((unsigned)v.x & 31u) << 5) | e;
                cnt += (code != kmincode);
            }
            nfb += ((unsigned)v.y <= limk);
        }
        kfinA[tid] = kmincode;
        out_idx[n0 + tid] = (float)kmincode;      // provisional for flagged
        if (cnt > 0 || nfb > 0) {
            const int ov = (cnt > 10 || nfb > 2);
            const int slot = atomicAdd(gcnt, 1);
            if (slot < REC_CAP) {
                int* rc = grec + slot * 16;
                rc[0] = n0 + tid;
                rc[1] = ov ? -1 : (cnt | (nfb << 8));
                rc[2] = kmincode;
                if (!ov) {                 // pass 3: write cands + fb trackers
                    int ic = 0, jf = 0;
                    for (int e = 0; e < 32; ++e) {
                        const int2 v = *reinterpret_cast<const int2*>(dmp + e * 8);
                        if ((unsigned)v.x <= limk) {
                            const int code = (int)(((unsigned)v.x & 31u) << 5) | e;
                            if (code != kmincode) { rc[3 + ic] = code; ++ic; }
                        }
                        if ((unsigned)v.y <= limk) { rc[13 + jf] = e; ++jf; }
                    }
                }
            }
        }
    }

    // ---- epilogue: gather code rows in two 32-row halves via [32][257] f32
#pragma unroll
    for (int h = 0; h < 2; ++h) {
        __syncthreads();
        {
            const int slot = tid & 31;
            const int cg   = tid >> 5;         // 8 col groups of 32
            const int kk   = kfinA[h * 32 + slot];
            const float4* er = reinterpret_cast<const float4*>(
                E + (size_t)kk * C_DIM + cg * 32);
            float* lb = reinterpret_cast<float*>(smraw) + slot * 257 + cg * 32;
#pragma unroll
            for (int i = 0; i < 8; ++i) {
                const float4 v = er[i];
                lb[4 * i + 0] = v.x; lb[4 * i + 1] = v.y;
                lb[4 * i + 2] = v.z; lb[4 * i + 3] = v.w;
            }
        }
        __syncthreads();
        {
            const int sg = tid & 31;
            const int cg = tid >> 5;
            float* ob = out_zq + (size_t)b * (C_DIM * S_DIM) + s0 + h * 32 + sg;
            const float* lr = reinterpret_cast<const float*>(smraw) + sg * 257;
#pragma unroll
            for (int i = 0; i < 32; ++i) {
                const int c = cg * 32 + i;
                ob[(size_t)c * S_DIM] = lr[c];
            }
        }
    }
}

// ---------------- phase 2: wave-parallel exact resolution ----------------
__global__ __launch_bounds__(256) void vq_fix2(
        const float* __restrict__ z, const float* __restrict__ E,
        const float* __restrict__ e2f, const float* __restrict__ zT,
        const int* __restrict__ gcnt, const int* __restrict__ grec,
        float* __restrict__ out_zq, float* __restrict__ out_idx) {
    __shared__ float zsh[256];
    __shared__ double dpart[4];
    __shared__ unsigned long long wbest[4];

    const int tid = threadIdx.x;
    const int w = tid >> 6, lane = tid & 63;
    int count = gcnt[0]; if (count > REC_CAP) count = REC_CAP;

    for (int ri = blockIdx.x; ri < count; ri += gridDim.x) {
        const int* rc = grec + ri * 16;
        const int n = rc[0], flags = rc[1], kmin = rc[2];
        const int b = n >> 13, s = n & (S_DIM - 1);
        __syncthreads();                   // guard LDS reuse across rows
        const float zc = zT ? zT[(size_t)n * C_DIM + tid]
                            : z[((size_t)(b * C_DIM + tid)) * S_DIM + s];
        zsh[tid] = zc;
        double p = (double)zc * (double)zc;
#pragma unroll
        for (int m = 32; m; m >>= 1) p += __shfl_xor(p, m, 64);
        if (lane == 0) dpart[w] = p;
        __syncthreads();
        const float znf = (float)((dpart[0] + dpart[1]) + (dpart[2] + dpart[3]));

        unsigned long long best = 0xFFFFFFFFFFFFFFFFull;
        if (flags >= 0) {
            const int cnt = flags & 0xFF, nfb = (flags >> 8) & 0xFF;
            const int total = 1 + cnt + 32 * nfb;
            const float4 zl4 = reinterpret_cast<const float4*>(zsh)[lane];
            for (int ci = w; ci < total; ci += 4) {    // waves independent
                int k;
                if (ci == 0) k = kmin;
                else if (ci <= cnt) k = rc[2 + ci];
                else {
                    const int t = ci - 1 - cnt;
                    k = ((t & 31) << 5) | rc[13 + (t >> 5)];
                }
                const float4 ev = reinterpret_cast<const float4*>(
                    E + (size_t)k * C_DIM)[lane];
                double dd = (double)zl4.x * ev.x + (double)zl4.y * ev.y
                          + (double)zl4.z * ev.z + (double)zl4.w * ev.w;
#pragma unroll
                for (int m = 32; m; m >>= 1) dd += __shfl_xor(dd, m, 64);
                const float t32 = (float)dd;
                const float A = znf + e2f[k];
                const float d = A - 2.0f * t32;        // > 0 always here
                best = ullmin2(best,
                    ((unsigned long long)__float_as_uint(d) << 32) | (unsigned)k);
            }
        } else {                           // ~never: per-thread 4-code full scan
            for (int j = 0; j < 4; ++j) {
                const int k = j * 256 + tid;
                const float4* er = reinterpret_cast<const float4*>(
                    E + (size_t)k * C_DIM);
                double dd = 0.0;
#pragma unroll 8
                for (int i = 0; i < 64; ++i) {
                    const float4 ev = er[i];
                    const float4 zl = reinterpret_cast<const float4*>(zsh)[i];
                    dd += (double)zl.x * ev.x + (double)zl.y * ev.y
                        + (double)zl.z * ev.z + (double)zl.w * ev.w;
                }
                const float t32 = (float)dd;
                const float d = (znf + e2f[k]) - 2.0f * t32;
                best = ullmin2(best,
                    ((unsigned long long)__float_as_uint(d) << 32) | (unsigned)k);
            }
#pragma unroll
            for (int m = 32; m; m >>= 1)
                best = ullmin2(best, (unsigned long long)__shfl_xor(
                    (long long)best, m, 64));
        }
        if (lane == 0) wbest[w] = best;
        __syncthreads();
        const unsigned long long fin =
            ullmin2(ullmin2(wbest[0], wbest[1]), ullmin2(wbest[2], wbest[3]));
        const int bk = (int)(fin & 0xFFFFFFFFull);
        if (bk != kmin) {                  // winner changed: rewrite outputs
            if (tid == 0) out_idx[n] = (float)bk;
            out_zq[((size_t)(b * C_DIM + tid)) * S_DIM + s] =
                E[(size_t)bk * C_DIM + tid];
        }
    }
}

extern "C" void kernel_launch(void* const* d_in, const int* in_sizes, int n_in,
                              void* d_out, int out_size, void* d_ws, size_t ws_size,
                              hipStream_t stream) {
    (void)in_sizes; (void)n_in; (void)out_size;
    const float* z = (const float*)d_in[0];
    const float* E = (const float*)d_in[1];
    char* wsb = (char*)d_ws;
    unsigned short* ehi = (unsigned short*)(wsb + WS_EHI);   // pre-swizzled
    float* e2f = (float*)(wsb + WS_E2F);
    int*   cnt = (int*)  (wsb + WS_CNT);
    int*   rec = (int*)  (wsb + WS_REC);
    float* zT  = (ws_size >= WS_NEED) ? (float*)(wsb + WS_ZT) : nullptr;
    float* out = (float*)d_out;

    hipMemsetAsync(cnt, 0, sizeof(int), stream);
    vq_prep<<<dim3(K_CODES), dim3(64), 0, stream>>>(E, ehi, e2f);
    vq_main<<<dim3(N_ROWS / TILE_M), dim3(256), 0, stream>>>(
        z, E, ehi, e2f, zT, out, out + ZQ_ELEMS, cnt, rec);
    vq_fix2<<<dim3(8192), dim3(256), 0, stream>>>(
        z, E, e2f, zT, cnt, rec, out, out + ZQ_ELEMS);
}

// Round 7
// 77.413 us; speedup vs baseline: 2.7969x; 1.0308x over previous
//
#include <hip/hip_runtime.h>
#include <hip/hip_bf16.h>

// VectorQuantizer on MI355X — single-pass bf16 MFMA screening GEMM (B operand
// loaded DIRECTLY into MFMA fragment registers from a pre-permuted codebook;
// no LDS staging, no barriers in the K-loop) + packed-key top-2 trackers +
// wave-parallel exact fp64 resolution of banded rows.
// Phase 1 (vq_main): d' = 1 + |e|^2 - 2*(zh . eh) via mfma_f32_16x16x32_bf16.
//   Per-lane tracker keeps top-2 keys key = bits(d')&~31 | chunk. Rows with
//   any other code within BAND1=1e-3 of the min are recorded. Emits zT
//   (compact f32 row-major z) for fix2's coalesced re-read.
// Phase 2 (vq_fix2): per record, exact numpy-fp32 pipeline (fp64 dot -> f32;
//   A = fl(zn+e2); d = fl(A-2t); lowest-index ties); waves parallel over
//   candidates; merged via packed u64 (bits(d)<<32 | k).
// d_out: z_q 8388608 f32, then indices 32768 as f32.

#define DEVI __device__ __forceinline__

typedef __attribute__((ext_vector_type(8))) short bf16x8;
typedef __attribute__((ext_vector_type(4))) float f32x4;

#define C_DIM   256
#define K_CODES 1024
#define S_DIM   8192
#define N_ROWS  32768
#define ZQ_ELEMS 8388608
#define TILE_M  64
#define NCHUNK  32
#define BAND1   1.0e-3f
#define REC_CAP 12288
#define FLT_BIG 3.402823466e+38f

// ws layout
#define WS_EFR  0                 // 512KB fragment-permuted bf16 codebook
#define WS_E2F  524288
#define WS_CNT  528384
#define WS_REC  528448            // REC_CAP x 64B
#define WS_ZT   1314880           // 32MB compact z transpose (optional)
#define WS_NEED (WS_ZT + (size_t)N_ROWS * C_DIM * 4)

DEVI unsigned short f2b(float f) {                 // fp32 -> bf16 RNE
    unsigned u = __float_as_uint(f);
    u += 0x7FFFu + ((u >> 16) & 1u);
    return (unsigned short)(u >> 16);
}
DEVI unsigned umin2(unsigned a, unsigned b) { return a < b ? a : b; }
DEVI unsigned umax2(unsigned a, unsigned b) { return a > b ? a : b; }
DEVI unsigned long long ullmin2(unsigned long long a, unsigned long long b) {
    return a < b ? a : b;
}

DEVI f32x4 MF(bf16x8 a, bf16x8 b, f32x4 c) {
    return __builtin_amdgcn_mfma_f32_16x16x32_bf16(a, b, c, 0, 0, 0);
}
DEVI bf16x8 ldsfrag(const char* L, int row, int coff) {
    const int byte = row * 512 + (coff ^ ((row & 7) << 4));
    return *reinterpret_cast<const bf16x8*>(L + byte);
}

// ---- prologue: codebook -> MFMA-fragment-permuted bf16 + exact f32 norms ----
// Fragment f (16B) of code k holds elems f*8..f*8+7 (contiguous bytes).
// Destination: efrag + chunk*16384 + wn*8192 + ks*1024 + (q*16+jj)*16,
// where chunk=k>>5, wn=(k>>4)&1, jj=k&15, ks=f>>2, q=f&3. A wave then loads
// its chunk-slice as lane*16 contiguous (lane = q*16+jj).
__global__ void vq_prep(const float* __restrict__ E,
                        unsigned short* __restrict__ efrag,
                        float* __restrict__ e2f) {
    const int k = blockIdx.x;          // 1024 blocks
    const int lane = threadIdx.x;      // 64 threads, 8B (half-fragment) each
    const float4 v = reinterpret_cast<const float4*>(E + (size_t)k * C_DIM)[lane];
    double s = (double)v.x * v.x + (double)v.y * v.y
             + (double)v.z * v.z + (double)v.w * v.w;
    ushort4 h;
    h.x = f2b(v.x); h.y = f2b(v.y); h.z = f2b(v.z); h.w = f2b(v.w);
    const int f = lane >> 1, half = lane & 1;
    const int ks = f >> 2, q = f & 3;
    const int jj = k & 15, wn = (k >> 4) & 1, chunk = k >> 5;
    char* dst = (char*)efrag + (size_t)chunk * 16384 + wn * 8192
              + ks * 1024 + (q * 16 + jj) * 16 + half * 8;
    *reinterpret_cast<ushort4*>(dst) = h;
#pragma unroll
    for (int m = 32; m; m >>= 1) s += __shfl_xor(s, m, 64);
    if (lane == 0) e2f[k] = (float)s;   // fp64-exact -> f32
}

// ---------------- phase 1 ----------------
__global__ __launch_bounds__(256, 2) void vq_main(
        const float* __restrict__ z, const float* __restrict__ E,
        const unsigned short* __restrict__ efrag,
        const float* __restrict__ e2f,
        float* __restrict__ zT,            // may be null
        float* __restrict__ out_zq, float* __restrict__ out_idx,
        int* __restrict__ gcnt, int* __restrict__ grec) {
    // smraw phases: A-hi stage 32KB -> key dump 17.4KB -> epi [32][257] 32.9KB
    __shared__ __align__(16) char smraw[32896];
    __shared__ float e2p[1024];        // 1.0f + |e_k|^2
    __shared__ int   kfinA[64];

    const int tid = threadIdx.x;
    const int n0 = blockIdx.x * TILE_M;
    const int b  = n0 >> 13;
    const int s0 = n0 & (S_DIM - 1);

    {   // e2p load
        const float4 v = reinterpret_cast<const float4*>(e2f)[tid];
        float4 w; w.x = 1.0f + v.x; w.y = 1.0f + v.y;
        w.z = 1.0f + v.z; w.w = 1.0f + v.w;
        reinterpret_cast<float4*>(e2p)[tid] = w;
    }

    // ---- stage A tile (hi only): z rows -> bf16, swizzled [64][512B];
    //      also emit compact f32 transpose zT[n][c] ----
    {
        const int s  = tid & 63;
        const int cg = tid >> 6;
        const float* zb = z + (size_t)b * (C_DIM * S_DIM) + s0 + s;
#pragma unroll
        for (int ci = 0; ci < 16; ++ci) {
            const int c = cg * 4 + ci * 16;
            const float x0 = zb[(size_t)(c + 0) * S_DIM];
            const float x1 = zb[(size_t)(c + 1) * S_DIM];
            const float x2 = zb[(size_t)(c + 2) * S_DIM];
            const float x3 = zb[(size_t)(c + 3) * S_DIM];
            ushort4 h;
            h.x = f2b(x0); h.y = f2b(x1); h.z = f2b(x2); h.w = f2b(x3);
            const int byte = s * 512 + ((c * 2) ^ ((s & 7) << 4));
            *reinterpret_cast<ushort4*>(smraw + byte) = h;
            if (zT) {
                float4 v; v.x = x0; v.y = x1; v.z = x2; v.w = x3;
                *reinterpret_cast<float4*>(zT + (size_t)(n0 + s) * C_DIM + c) = v;
            }
        }
    }
    __syncthreads();

    const int w    = tid >> 6;
    const int lane = tid & 63;
    const int wm   = w >> 1, wn = w & 1;
    const int q    = lane >> 4, jj = lane & 15;
    const int mycol = wn * 16 + jj;        // tracker/entry id 0..31

    bf16x8 Ah0[8], Ah1[8];
    {
        const int r0 = wm * 32 + jj, r1 = r0 + 16;
#pragma unroll
        for (int ks = 0; ks < 8; ++ks) {
            const int coff = ks * 64 + q * 16;
            Ah0[ks] = ldsfrag(smraw, r0, coff);
            Ah1[ks] = ldsfrag(smraw, r1, coff);
        }
    }
    // NOTE: no further barrier needed until the key dump (smraw untouched).

    // ---- main K-loop: B fragments straight from global into registers ----
    const char* gB = (const char*)efrag + (size_t)wn * 8192 + (size_t)lane * 16;

#define LOADB(BR, N)                                                          \
    { _Pragma("unroll")                                                       \
      for (int ks_ = 0; ks_ < 8; ++ks_)                                       \
          BR[ks_] = *reinterpret_cast<const bf16x8*>(                         \
              gB + (size_t)(N) * 16384 + ks_ * 1024); }

#define RCOMPUTE(BR, A0, A1)                                                  \
    { A0 = (f32x4){0.f, 0.f, 0.f, 0.f}; A1 = A0;                              \
      _Pragma("unroll")                                                       \
      for (int ks_ = 0; ks_ < 8; ++ks_) {                                     \
          A0 = MF(Ah0[ks_], BR[ks_], A0);                                     \
          A1 = MF(Ah1[ks_], BR[ks_], A1);                                     \
      } }

#define UPD(A0, A1, E2V, N)                                                   \
    { _Pragma("unroll")                                                       \
      for (int r = 0; r < 4; ++r) {                                           \
          unsigned t_ = (__float_as_uint(                                     \
              __builtin_fmaf(-2.f, A0[r], E2V)) & 0xFFFFFFE0u) | (unsigned)(N);\
          unsigned lo_ = umin2(K1[r], t_), hi_ = umax2(K1[r], t_);            \
          K1[r] = lo_; K2[r] = umin2(K2[r], hi_);                             \
          t_ = (__float_as_uint(                                              \
              __builtin_fmaf(-2.f, A1[r], E2V)) & 0xFFFFFFE0u) | (unsigned)(N);\
          lo_ = umin2(K1[4 + r], t_); hi_ = umax2(K1[4 + r], t_);             \
          K1[4 + r] = lo_; K2[4 + r] = umin2(K2[4 + r], hi_);                 \
      } }

    unsigned K1[8], K2[8];
#pragma unroll
    for (int i = 0; i < 8; ++i) { K1[i] = 0xFFFFFFFFu; K2[i] = 0xFFFFFFFFu; }

    bf16x8 Bc[8], Bn[8];
    LOADB(Bc, 0)
    LOADB(Bn, 1)
    f32x4 aA0, aA1, aB0, aB1;

#pragma unroll
    for (int p = 0; p < 16; ++p) {
        const int nA = 2 * p, nB = 2 * p + 1;
        RCOMPUTE(Bc, aA0, aA1)
        if (p < 15) LOADB(Bc, nA + 2)
        UPD(aA0, aA1, e2p[nA * 32 + mycol], nA)
        RCOMPUTE(Bn, aB0, aB1)
        if (p < 15) LOADB(Bn, nB + 2)
        UPD(aB0, aB1, e2p[nB * 32 + mycol], nB)
    }

    // ---- dump per-tracker top-2 keys: [64 rows][32 entries] int2, 272B rows
    __syncthreads();                       // A-frag reads done; smraw reusable
#pragma unroll
    for (int t = 0; t < 2; ++t) {
#pragma unroll
        for (int r = 0; r < 4; ++r) {
            const int sl = t * 4 + r;
            const int row = wm * 32 + t * 16 + q * 4 + r;
            *reinterpret_cast<int2*>(smraw + row * 272 + mycol * 8) =
                make_int2((int)K1[sl], (int)K2[sl]);
        }
    }
    __syncthreads();

    // ---- leader: winner + banded candidate records (3 passes, no scratch) --
    if (tid < 64) {
        const char* dmp = smraw + tid * 272;
        unsigned kmin = 0xFFFFFFFFu; int emin = 0;
#pragma unroll 4
        for (int e = 0; e < 32; ++e) {
            const unsigned k1 = (unsigned)
                reinterpret_cast<const int2*>(dmp + e * 8)->x;
            if (k1 < kmin) { kmin = k1; emin = e; }
        }
        const int kmincode = (int)((kmin & 31u) << 5) | emin;
        const float dminf = __uint_as_float(kmin & 0xFFFFFFE0u);
        const unsigned limk =
            (__float_as_uint(dminf + BAND1) & 0xFFFFFFE0u) | 31u;
        int cnt = 0, nfb = 0;
#pragma unroll 4
        for (int e = 0; e < 32; ++e) {
            const int2 v = *reinterpret_cast<const int2*>(dmp + e * 8);
            if ((unsigned)v.x <= limk) {
                const int code = (int)(((unsigned)v.x & 31u) << 5) | e;
                cnt += (code != kmincode);
            }
            nfb += ((unsigned)v.y <= limk);
        }
        kfinA[tid] = kmincode;
        out_idx[n0 + tid] = (float)kmincode;      // provisional for flagged
        if (cnt > 0 || nfb > 0) {
            const int ov = (cnt > 10 || nfb > 2);
            const int slot = atomicAdd(gcnt, 1);
            if (slot < REC_CAP) {
                int* rc = grec + slot * 16;
                rc[0] = n0 + tid;
                rc[1] = ov ? -1 : (cnt | (nfb << 8));
                rc[2] = kmincode;
                if (!ov) {                 // pass 3: write cands + fb trackers
                    int ic = 0, jf = 0;
                    for (int e = 0; e < 32; ++e) {
                        const int2 v = *reinterpret_cast<const int2*>(dmp + e * 8);
                        if ((unsigned)v.x <= limk) {
                            const int code = (int)(((unsigned)v.x & 31u) << 5) | e;
                            if (code != kmincode) { rc[3 + ic] = code; ++ic; }
                        }
                        if ((unsigned)v.y <= limk) { rc[13 + jf] = e; ++jf; }
                    }
                }
            }
        }
    }

    // ---- epilogue: gather code rows in two 32-row halves via [32][257] f32
#pragma unroll
    for (int h = 0; h < 2; ++h) {
        __syncthreads();
        {
            const int slot = tid & 31;
            const int cg   = tid >> 5;         // 8 col groups of 32
            const int kk   = kfinA[h * 32 + slot];
            const float4* er = reinterpret_cast<const float4*>(
                E + (size_t)kk * C_DIM + cg * 32);
            float* lb = reinterpret_cast<float*>(smraw) + slot * 257 + cg * 32;
#pragma unroll
            for (int i = 0; i < 8; ++i) {
                const float4 v = er[i];
                lb[4 * i + 0] = v.x; lb[4 * i + 1] = v.y;
                lb[4 * i + 2] = v.z; lb[4 * i + 3] = v.w;
            }
        }
        __syncthreads();
        {
            const int sg = tid & 31;
            const int cg = tid >> 5;
            float* ob = out_zq + (size_t)b * (C_DIM * S_DIM) + s0 + h * 32 + sg;
            const float* lr = reinterpret_cast<const float*>(smraw) + sg * 257;
#pragma unroll
            for (int i = 0; i < 32; ++i) {
                const int c = cg * 32 + i;
                ob[(size_t)c * S_DIM] = lr[c];
            }
        }
    }
}

// ---------------- phase 2: wave-parallel exact resolution ----------------
__global__ __launch_bounds__(256) void vq_fix2(
        const float* __restrict__ z, const float* __restrict__ E,
        const float* __restrict__ e2f, const float* __restrict__ zT,
        const int* __restrict__ gcnt, const int* __restrict__ grec,
        float* __restrict__ out_zq, float* __restrict__ out_idx) {
    __shared__ float zsh[256];
    __shared__ double dpart[4];
    __shared__ unsigned long long wbest[4];

    const int tid = threadIdx.x;
    const int w = tid >> 6, lane = tid & 63;
    int count = gcnt[0]; if (count > REC_CAP) count = REC_CAP;

    for (int ri = blockIdx.x; ri < count; ri += gridDim.x) {
        const int* rc = grec + ri * 16;
        const int n = rc[0], flags = rc[1], kmin = rc[2];
        const int b = n >> 13, s = n & (S_DIM - 1);
        __syncthreads();                   // guard LDS reuse across rows
        const float zc = zT ? zT[(size_t)n * C_DIM + tid]
                            : z[((size_t)(b * C_DIM + tid)) * S_DIM + s];
        zsh[tid] = zc;
        double p = (double)zc * (double)zc;
#pragma unroll
        for (int m = 32; m; m >>= 1) p += __shfl_xor(p, m, 64);
        if (lane == 0) dpart[w] = p;
        __syncthreads();
        const float znf = (float)((dpart[0] + dpart[1]) + (dpart[2] + dpart[3]));

        unsigned long long best = 0xFFFFFFFFFFFFFFFFull;
        if (flags >= 0) {
            const int cnt = flags & 0xFF, nfb = (flags >> 8) & 0xFF;
            const int total = 1 + cnt + 32 * nfb;
            const float4 zl4 = reinterpret_cast<const float4*>(zsh)[lane];
            for (int ci = w; ci < total; ci += 4) {    // waves independent
                int k;
                if (ci == 0) k = kmin;
                else if (ci <= cnt) k = rc[2 + ci];
                else {
                    const int t = ci - 1 - cnt;
                    k = ((t & 31) << 5) | rc[13 + (t >> 5)];
                }
                const float4 ev = reinterpret_cast<const float4*>(
                    E + (size_t)k * C_DIM)[lane];
                double dd = (double)zl4.x * ev.x + (double)zl4.y * ev.y
                          + (double)zl4.z * ev.z + (double)zl4.w * ev.w;
#pragma unroll
                for (int m = 32; m; m >>= 1) dd += __shfl_xor(dd, m, 64);
                const float t32 = (float)dd;
                const float A = znf + e2f[k];
                const float d = A - 2.0f * t32;        // > 0 always here
                best = ullmin2(best,
                    ((unsigned long long)__float_as_uint(d) << 32) | (unsigned)k);
            }
        } else {                           // ~never: per-thread 4-code full scan
            for (int j = 0; j < 4; ++j) {
                const int k = j * 256 + tid;
                const float4* er = reinterpret_cast<const float4*>(
                    E + (size_t)k * C_DIM);
                double dd = 0.0;
#pragma unroll 8
                for (int i = 0; i < 64; ++i) {
                    const float4 ev = er[i];
                    const float4 zl = reinterpret_cast<const float4*>(zsh)[i];
                    dd += (double)zl.x * ev.x + (double)zl.y * ev.y
                        + (double)zl.z * ev.z + (double)zl.w * ev.w;
                }
                const float t32 = (float)dd;
                const float d = (znf + e2f[k]) - 2.0f * t32;
                best = ullmin2(best,
                    ((unsigned long long)__float_as_uint(d) << 32) | (unsigned)k);
            }
#pragma unroll
            for (int m = 32; m; m >>= 1)
                best = ullmin2(best, (unsigned long long)__shfl_xor(
                    (long long)best, m, 64));
        }
        if (lane == 0) wbest[w] = best;
        __syncthreads();
        const unsigned long long fin =
            ullmin2(ullmin2(wbest[0], wbest[1]), ullmin2(wbest[2], wbest[3]));
        const int bk = (int)(fin & 0xFFFFFFFFull);
        if (bk != kmin) {                  // winner changed: rewrite outputs
            if (tid == 0) out_idx[n] = (float)bk;
            out_zq[((size_t)(b * C_DIM + tid)) * S_DIM + s] =
                E[(size_t)bk * C_DIM + tid];
        }
    }
}

extern "C" void kernel_launch(void* const* d_in, const int* in_sizes, int n_in,
                              void* d_out, int out_size, void* d_ws, size_t ws_size,
                              hipStream_t stream) {
    (void)in_sizes; (void)n_in; (void)out_size;
    const float* z = (const float*)d_in[0];
    const float* E = (const float*)d_in[1];
    char* wsb = (char*)d_ws;
    unsigned short* efrag = (unsigned short*)(wsb + WS_EFR); // frag-permuted
    float* e2f = (float*)(wsb + WS_E2F);
    int*   cnt = (int*)  (wsb + WS_CNT);
    int*   rec = (int*)  (wsb + WS_REC);
    float* zT  = (ws_size >= WS_NEED) ? (float*)(wsb + WS_ZT) : nullptr;
    float* out = (float*)d_out;

    hipMemsetAsync(cnt, 0, sizeof(int), stream);
    vq_prep<<<dim3(K_CODES), dim3(64), 0, stream>>>(E, efrag, e2f);
    vq_main<<<dim3(N_ROWS / TILE_M), dim3(256), 0, stream>>>(
        z, E, efrag, e2f, zT, out, out + ZQ_ELEMS, cnt, rec);
    vq_fix2<<<dim3(2048), dim3(256), 0, stream>>>(
        z, E, e2f, zT, cnt, rec, out, out + ZQ_ELEMS);
}